// Round 11
// baseline (800.961 us; speedup 1.0000x reference)
//
#include <hip/hip_runtime.h>
#include <math.h>

#define NN 100000
#define NPAD 100096
#define NT2 1564      // NPAD / 64 (gru blocks)
#define NE 800000
#define DD 128
#define SCANB 98      // ceil(NN/1024)

typedef __attribute__((ext_vector_type(8))) short short8;
typedef __attribute__((ext_vector_type(4))) float floatx4;
typedef unsigned short ush_t;
typedef __attribute__((ext_vector_type(8))) unsigned short ushort8_t;

__device__ __forceinline__ ush_t f2bf(float f) {
    unsigned u = __float_as_uint(f);
    return (ush_t)((u + 0x7fffu + ((u >> 16) & 1u)) >> 16);
}
__device__ __forceinline__ float bf2f(ush_t h) {
    return __uint_as_float((unsigned)h << 16);
}
__device__ __forceinline__ float sigf(float x) {
    return __builtin_amdgcn_rcpf(1.0f + __expf(-x));
}
__device__ __forceinline__ float tanhf_fast(float x) {
    x = fminf(fmaxf(x, -20.0f), 20.0f);
    float e = __expf(2.0f * x);
    return 1.0f - 2.0f * __builtin_amdgcn_rcpf(e + 1.0f);
}

// ---------------------------------------------------------------- row means of edge-type table
__global__ void rowmean_kernel(const float* __restrict__ tab, float* __restrict__ rm) {
    int r = blockIdx.x;
    int t = threadIdx.x;
    float v = tab[r * DD + t];
    #pragma unroll
    for (int o = 32; o > 0; o >>= 1) v += __shfl_xor(v, o);
    __shared__ float red[2];
    if ((t & 63) == 0) red[t >> 6] = v;
    __syncthreads();
    if (t == 0) rm[r] = (red[0] + red[1]) * (1.0f / DD);
}

// ---------------------------------------------------------------- CSR build
__global__ void hist_kernel(const int* __restrict__ dst, int* __restrict__ fill) {
    int e = blockIdx.x * 256 + threadIdx.x;
    if (e < NE) atomicAdd(&fill[dst[e]], 1);
}

__global__ __launch_bounds__(1024) void scanA_kernel(const int* __restrict__ cnt,
                                                     int* __restrict__ rp,
                                                     int* __restrict__ bsum) {
    __shared__ int wsum[16];
    int t = threadIdx.x;
    int i = blockIdx.x * 1024 + t;
    int lane = t & 63, w = t >> 6;
    int v = (i < NN) ? cnt[i] : 0;
    int sv = v;
    #pragma unroll
    for (int off = 1; off < 64; off <<= 1) {
        int u = __shfl_up(sv, off);
        if (lane >= off) sv += u;
    }
    if (lane == 63) wsum[w] = sv;
    __syncthreads();
    int woff = 0;
    #pragma unroll
    for (int j = 0; j < 16; ++j) woff += (j < w) ? wsum[j] : 0;
    if (i < NN) rp[i + 1] = sv + woff;
    if (t == 1023) bsum[blockIdx.x] = sv + woff;
}

__global__ __launch_bounds__(128) void scanB_kernel(const int* __restrict__ bsum,
                                                    int* __restrict__ boff) {
    __shared__ int wsum[2];
    int t = threadIdx.x;
    int lane = t & 63, w = t >> 6;
    int v = (t < SCANB) ? bsum[t] : 0;
    int sv = v;
    #pragma unroll
    for (int off = 1; off < 64; off <<= 1) {
        int u = __shfl_up(sv, off);
        if (lane >= off) sv += u;
    }
    if (lane == 63) wsum[w] = sv;
    __syncthreads();
    int woff = (w == 1) ? wsum[0] : 0;
    if (t < SCANB) boff[t] = sv + woff - v;   // exclusive
}

__global__ __launch_bounds__(256) void scanC_kernel(int* __restrict__ rp,
                                                    const int* __restrict__ boff) {
    int i = blockIdx.x * 256 + threadIdx.x;
    if (i == 0) rp[0] = 0;
    if (i < NN) rp[i + 1] += boff[i >> 10];
}

__global__ void place_kernel(const int* __restrict__ src, const int* __restrict__ dst,
                             const int* __restrict__ et, const float* __restrict__ rm,
                             const int* __restrict__ rp, int* __restrict__ fill,
                             int* __restrict__ csr_s, float* __restrict__ csr_w) {
    int e = blockIdx.x * 256 + threadIdx.x;
    if (e < NE) {
        int d = dst[e];
        int pos = rp[d] + atomicAdd(&fill[d], 1);
        csr_s[pos] = src[e];
        csr_w[pos] = rm[et[e] - 1];
    }
}

// ---------------------------------------------------------------- embedding gather → bf16 row-major
__global__ void embed_kernel(const int* __restrict__ ids, const float* __restrict__ tab,
                             ush_t* __restrict__ x) {
    int tid = blockIdx.x * 256 + threadIdx.x;   // NPAD*16
    int n = tid >> 4, c = tid & 15;
    if (n >= NPAD) return;
    ushort8_t h;
    if (n < NN) {
        const float4* srcp = (const float4*)(tab + (size_t)(ids[n] + 1) * DD + c * 8);
        float4 v0 = srcp[0], v1 = srcp[1];
        h[0] = f2bf(v0.x); h[1] = f2bf(v0.y); h[2] = f2bf(v0.z); h[3] = f2bf(v0.w);
        h[4] = f2bf(v1.x); h[5] = f2bf(v1.y); h[6] = f2bf(v1.z); h[7] = f2bf(v1.w);
    } else {
        #pragma unroll
        for (int e = 0; e < 8; ++e) h[e] = 0;
    }
    *(ushort8_t*)(x + (size_t)n * DD + c * 8) = h;
}

// ---------------------------------------------------------------- weight prep: Whh gates → WB mats 0..2
__global__ void wprep_kernel(const float* __restrict__ Whh, ush_t* __restrict__ WB) {
    int idx = blockIdx.x * 256 + threadIdx.x;   // 3*16384
    int mat = idx >> 14;
    int rem = idx & 16383;
    int col = rem & 127, kk = rem >> 7;
    float w = Whh[((size_t)mat * 128 + col) * 128 + kk];
    int chunk = kk >> 5, klo = kk & 31;
    int inoff = ((col >> 4) * 4 + (klo >> 3)) * 128 + (col & 15) * 8 + (klo & 7);
    WB[(size_t)(mat * 4 + chunk) * 4096 + inoff] = f2bf(w);
}

// ---------------------------------------------------------------- combined weights: C[l,g] = W_l @ Wih_g^T
// WB mats 3 + l*3 + g. C[k,col] = sum_j W_l[k,j] * Wih[g*128+col, j]
__global__ __launch_bounds__(256) void cprep_kernel(const float* __restrict__ Wih,
                                                    const float* __restrict__ G,
                                                    ush_t* __restrict__ WB) {
    __shared__ float sW[16 * 128];
    int b = blockIdx.x;                 // 96 = 12 mats * 8 rowgroups
    int mat = b >> 3, rg = b & 7;
    int l = mat / 3, g = mat % 3;
    int k0 = rg * 16;
    int t = threadIdx.x;
    #pragma unroll
    for (int it = 0; it < 8; ++it) {
        int idx = it * 256 + t;         // 2048: row kk=idx>>7, j=idx&127
        sW[idx] = G[(size_t)l * 16384 + (size_t)(k0 + (idx >> 7)) * 128 + (idx & 127)];
    }
    __syncthreads();
    int col = t & 127, kh = t >> 7;
    float acc[8];
    #pragma unroll
    for (int e = 0; e < 8; ++e) acc[e] = 0.f;
    const float* wr = Wih + (size_t)(g * 128 + col) * 128;
    for (int j = 0; j < 128; ++j) {
        float wv = wr[j];
        #pragma unroll
        for (int e = 0; e < 8; ++e) acc[e] += sW[(kh * 8 + e) * 128 + j] * wv;
    }
    int M = 3 + l * 3 + g;
    #pragma unroll
    for (int e = 0; e < 8; ++e) {
        int k = k0 + kh * 8 + e;
        int chunk = k >> 5, klo = k & 31;
        int inoff = ((col >> 4) * 4 + (klo >> 3)) * 128 + (col & 15) * 8 + (klo & 7);
        WB[(size_t)(M * 4 + chunk) * 4096 + inoff] = f2bf(acc[e]);
    }
}

// ---------------------------------------------------------------- mega-fused layer kernel
// phase A: stage x tile (row-major bf16) → sX
// phase B: gather g = sum ew*x[src] → sG (bf16)
// phase C: MFMA pass-0 x@Whh^T, pass-1 g@C_l (A-frags from LDS)
// phase D: GRU gates in-place into sX
// phase E: row-major write-out (layers 0-2) OR fused pooling (layer 3)
__global__ __launch_bounds__(256, 3) void gru_kernel(const ush_t* __restrict__ xin,
                                                     ush_t* __restrict__ xout,
                                                     const int* __restrict__ rp,
                                                     const int* __restrict__ csr_s,
                                                     const float* __restrict__ csr_w,
                                                     const ush_t* __restrict__ WB,
                                                     const float* __restrict__ bih,
                                                     const float* __restrict__ bhh,
                                                     int layer, int is_last,
                                                     const float* __restrict__ gw,
                                                     const float* __restrict__ gb,
                                                     float* __restrict__ accum,
                                                     float* __restrict__ den) {
    __shared__ ush_t sX[64 * 136];
    __shared__ ush_t sG[64 * 136];
    __shared__ float pl[64];
    __shared__ float sT[128];
    int t = threadIdx.x;
    int tb = blockIdx.x;
    int n0 = tb * 64;
    // --- A: stage x tile
    #pragma unroll
    for (int it = 0; it < 4; ++it) {
        int idx = it * 256 + t;          // 1024 chunks of 16B
        int row = idx >> 4, seg = idx & 15;
        ushort8_t v = *(const ushort8_t*)(xin + (size_t)(n0 + row) * DD + seg * 8);
        *(ushort8_t*)(sX + row * 136 + seg * 8) = v;
    }
    // --- B: gather
    int hw = t >> 5, c = t & 31;
    #pragma unroll 1
    for (int it = 0; it < 8; ++it) {
        int nl = hw * 8 + it;
        int n = n0 + nl;
        float4 acc = make_float4(0.f, 0.f, 0.f, 0.f);
        if (n < NN) {
            int e0 = rp[n], e1 = rp[n + 1];
            int e = e0;
            for (; e + 1 < e1; e += 2) {
                float w0 = csr_w[e], w1 = csr_w[e + 1];
                int s0 = csr_s[e], s1 = csr_s[e + 1];
                ushort4 p0 = *(const ushort4*)(xin + (size_t)s0 * DD + c * 4);
                ushort4 p1 = *(const ushort4*)(xin + (size_t)s1 * DD + c * 4);
                acc.x += w0 * bf2f(p0.x) + w1 * bf2f(p1.x);
                acc.y += w0 * bf2f(p0.y) + w1 * bf2f(p1.y);
                acc.z += w0 * bf2f(p0.z) + w1 * bf2f(p1.z);
                acc.w += w0 * bf2f(p0.w) + w1 * bf2f(p1.w);
            }
            if (e < e1) {
                float w0 = csr_w[e];
                int s0 = csr_s[e];
                ushort4 p0 = *(const ushort4*)(xin + (size_t)s0 * DD + c * 4);
                acc.x += w0 * bf2f(p0.x);
                acc.y += w0 * bf2f(p0.y);
                acc.z += w0 * bf2f(p0.z);
                acc.w += w0 * bf2f(p0.w);
            }
        }
        ushort4 o;
        o.x = f2bf(acc.x); o.y = f2bf(acc.y); o.z = f2bf(acc.z); o.w = f2bf(acc.w);
        *(ushort4*)(sG + nl * 136 + c * 4) = o;
    }
    __syncthreads();
    // --- C: MFMA
    int l = t & 63, w = t >> 6;
    int lg = l >> 4, lc = l & 15;
    floatx4 accR[4][2], accZ[4][2], accN[4][2], accI[4][2];
    #pragma unroll
    for (int i = 0; i < 4; ++i)
        #pragma unroll
        for (int j = 0; j < 2; ++j) {
            accR[i][j] = (floatx4)0.f; accZ[i][j] = (floatx4)0.f;
            accN[i][j] = (floatx4)0.f; accI[i][j] = (floatx4)0.f;
        }
    #pragma unroll
    for (int pass = 0; pass < 2; ++pass) {
        const ush_t* Ap = pass ? sG : sX;
        int matbase = pass ? (3 + layer * 3) : 0;
        #pragma unroll
        for (int kc = 0; kc < 4; ++kc) {
            short8 aHf[4];
            #pragma unroll
            for (int i = 0; i < 4; ++i)
                aHf[i] = *(const short8*)(Ap + (i * 16 + lc) * 136 + kc * 32 + lg * 8);
            #pragma unroll
            for (int m3 = 0; m3 < 3; ++m3) {
                floatx4 (*accp)[2] = (m3 == 0) ? accR : (m3 == 1) ? accZ : (pass ? accI : accN);
                const ush_t* wb = WB + (size_t)((matbase + m3) * 4 + kc) * 4096;
                #pragma unroll
                for (int j = 0; j < 2; ++j) {
                    int boff = (((w * 2 + j) * 4 + lg) * 16 + lc) * 8;
                    short8 bH = *(const short8*)(wb + boff);
                    #pragma unroll
                    for (int i = 0; i < 4; ++i)
                        accp[i][j] = __builtin_amdgcn_mfma_f32_16x16x32_bf16(aHf[i], bH, accp[i][j], 0, 0, 0);
                }
            }
        }
    }
    __syncthreads();   // all sX/sG A-frag reads done before sX overwrite
    // --- D: gates + blend, in-place into sX
    #pragma unroll
    for (int j = 0; j < 2; ++j) {
        int col = w * 32 + j * 16 + lc;
        float bIr = bih[col],       bHr = bhh[col];
        float bIz = bih[128 + col], bHz = bhh[128 + col];
        float bIn = bih[256 + col], bHn = bhh[256 + col];
        #pragma unroll
        for (int i = 0; i < 4; ++i)
            #pragma unroll
            for (int r = 0; r < 4; ++r) {
                int row = i * 16 + lg * 4 + r;
                float v = 0.f;
                if (n0 + row < NN) {
                    float rr = sigf(accR[i][j][r] + bIr + bHr);
                    float zz = sigf(accZ[i][j][r] + bIz + bHz);
                    float nn = tanhf_fast(accI[i][j][r] + bIn + rr * (accN[i][j][r] + bHn));
                    float h = bf2f(sX[row * 136 + col]);
                    v = (1.0f - zz) * nn + zz * h;
                }
                sX[row * 136 + col] = f2bf(v);
            }
    }
    __syncthreads();
    if (!is_last) {
        // --- E: coalesced row-major write-out
        #pragma unroll
        for (int it = 0; it < 4; ++it) {
            int idx = it * 256 + t;
            int row = idx >> 4, seg = idx & 15;
            ushort8_t v = *(const ushort8_t*)(sX + row * 136 + seg * 8);
            *(ushort8_t*)(xout + (size_t)(n0 + row) * DD + seg * 8) = v;
        }
    } else {
        // --- E': fused global-attention pooling (replicated accumulators)
        int row = t >> 2, q = t & 3;
        float s = 0.f;
        #pragma unroll
        for (int e = 0; e < 32; ++e)
            s += bf2f(sX[row * 136 + q * 32 + e]) * gw[q * 32 + e];
        s += __shfl_xor(s, 1);
        s += __shfl_xor(s, 2);
        if (q == 0)
            pl[row] = (n0 + row < NN) ? __expf(sigf(s + gb[0])) : 0.f;
        __syncthreads();
        int cc = t & 127, half = t >> 7;
        float acc = 0.f;
        #pragma unroll
        for (int r = 0; r < 32; ++r)
            acc += pl[half * 32 + r] * bf2f(sX[(half * 32 + r) * 136 + cc]);
        if (half == 0) sT[cc] = acc;
        __syncthreads();
        if (half == 1) atomicAdd(&accum[(tb & 63) * 128 + cc], acc + sT[cc]);
        if (t < 64) {
            float v = pl[t];
            #pragma unroll
            for (int o = 32; o > 0; o >>= 1) v += __shfl_xor(v, o);
            if (t == 0) atomicAdd(&den[tb & 63], v);
        }
    }
}

__global__ void finalize_kernel(const float* __restrict__ accum, const float* __restrict__ den,
                                float* __restrict__ out) {
    __shared__ float dsum;
    int d = threadIdx.x;   // 128
    float s = 0.f;
    for (int rep = 0; rep < 64; ++rep) s += accum[rep * 128 + d];
    if (d == 0) {
        float ds = 0.f;
        for (int rep = 0; rep < 64; ++rep) ds += den[rep];
        dsum = ds;
    }
    __syncthreads();
    out[d] = s / dsum;
}

// ---------------------------------------------------------------- launch
extern "C" void kernel_launch(void* const* d_in, const int* in_sizes, int n_in,
                              void* d_out, int out_size, void* d_ws, size_t ws_size,
                              hipStream_t stream) {
    const int*   node_ids    = (const int*)d_in[0];
    const int*   edges       = (const int*)d_in[1];
    const int*   edge_types  = (const int*)d_in[2];
    const float* embed_table = (const float*)d_in[3];
    const float* edge_tab    = (const float*)d_in[4];
    const float* ggnn_w      = (const float*)d_in[5];
    const float* Wih         = (const float*)d_in[6];
    const float* Whh         = (const float*)d_in[7];
    const float* bih         = (const float*)d_in[8];
    const float* bhh         = (const float*)d_in[9];
    const float* gate_w      = (const float*)d_in[10];
    const float* gate_b      = (const float*)d_in[11];
    float* out = (float*)d_out;

    const size_t PL = (size_t)NPAD * DD;
    ush_t* wsb  = (ush_t*)d_ws;
    ush_t* xA   = wsb;
    ush_t* xB   = xA + PL;
    ush_t* WB   = xB + PL;          // 15 mats * 4 chunks * 4096
    float* csr_w = (float*)(WB + 15 * 4 * 4096);
    float* accum = csr_w + NE;      // 64 * 128
    float* den   = accum + 64 * 128; // 64
    float* rm    = den + 64;        // 7(+1)
    int*   rp    = (int*)(rm + 8);  // N+1
    int*   fill  = rp + NN + 1;     // N
    int*   csr_s = fill + NN;       // E
    int*   bsum  = csr_s + NE;      // 128
    int*   boff  = bsum + 128;      // 128

    const int* src = edges;
    const int* dst = edges + NE;

    // one-time prep
    rowmean_kernel<<<7, 128, 0, stream>>>(edge_tab, rm);
    hipMemsetAsync(fill, 0, NN * sizeof(int), stream);
    hist_kernel<<<(NE + 255) / 256, 256, 0, stream>>>(dst, fill);
    scanA_kernel<<<SCANB, 1024, 0, stream>>>(fill, rp, bsum);
    scanB_kernel<<<1, 128, 0, stream>>>(bsum, boff);
    scanC_kernel<<<(NN + 255) / 256, 256, 0, stream>>>(rp, boff);
    hipMemsetAsync(fill, 0, NN * sizeof(int), stream);
    place_kernel<<<(NE + 255) / 256, 256, 0, stream>>>(src, dst, edge_types, rm, rp, fill,
                                                       csr_s, csr_w);
    embed_kernel<<<NPAD * 16 / 256, 256, 0, stream>>>(node_ids, embed_table, xA);
    wprep_kernel<<<192, 256, 0, stream>>>(Whh, WB);
    cprep_kernel<<<96, 256, 0, stream>>>(Wih, ggnn_w, WB);
    hipMemsetAsync(accum, 0, (64 * 128 + 64) * sizeof(float), stream);

    // 4 fused layers
    ush_t* x = xA;
    ush_t* xo = xB;
    for (int layer = 0; layer < 4; ++layer) {
        gru_kernel<<<NT2, 256, 0, stream>>>(x, xo, rp, csr_s, csr_w, WB, bih, bhh,
                                            layer, layer == 3 ? 1 : 0,
                                            gate_w, gate_b, accum, den);
        ush_t* tmp = x; x = xo; xo = tmp;
    }

    finalize_kernel<<<1, 128, 0, stream>>>(accum, den, out);
}

// Round 12
// 788.560 us; speedup vs baseline: 1.0157x; 1.0157x over previous
//
#include <hip/hip_runtime.h>
#include <math.h>

#define NN 100000
#define NPAD 100096
#define NT2 1564      // NPAD / 64 (gru blocks)
#define NE 800000
#define DD 128
#define SCANB 98      // ceil(NN/1024)

typedef __attribute__((ext_vector_type(8))) short short8;
typedef __attribute__((ext_vector_type(4))) float floatx4;
typedef unsigned short ush_t;
typedef __attribute__((ext_vector_type(8))) unsigned short ushort8_t;

__device__ __forceinline__ ush_t f2bf(float f) {
    unsigned u = __float_as_uint(f);
    return (ush_t)((u + 0x7fffu + ((u >> 16) & 1u)) >> 16);
}
__device__ __forceinline__ float bf2f(ush_t h) {
    return __uint_as_float((unsigned)h << 16);
}
__device__ __forceinline__ float sigf(float x) {
    return __builtin_amdgcn_rcpf(1.0f + __expf(-x));
}
__device__ __forceinline__ float tanhf_fast(float x) {
    x = fminf(fmaxf(x, -20.0f), 20.0f);
    float e = __expf(2.0f * x);
    return 1.0f - 2.0f * __builtin_amdgcn_rcpf(e + 1.0f);
}

// ---------------------------------------------------------------- row means of edge-type table
__global__ void rowmean_kernel(const float* __restrict__ tab, float* __restrict__ rm) {
    int r = blockIdx.x;
    int t = threadIdx.x;
    float v = tab[r * DD + t];
    #pragma unroll
    for (int o = 32; o > 0; o >>= 1) v += __shfl_xor(v, o);
    __shared__ float red[2];
    if ((t & 63) == 0) red[t >> 6] = v;
    __syncthreads();
    if (t == 0) rm[r] = (red[0] + red[1]) * (1.0f / DD);
}

// ---------------------------------------------------------------- CSR build
__global__ void hist_kernel(const int* __restrict__ dst, int* __restrict__ fill) {
    int e = blockIdx.x * 256 + threadIdx.x;
    if (e < NE) atomicAdd(&fill[dst[e]], 1);
}

__global__ __launch_bounds__(1024) void scanA_kernel(const int* __restrict__ cnt,
                                                     int* __restrict__ rp,
                                                     int* __restrict__ bsum) {
    __shared__ int wsum[16];
    int t = threadIdx.x;
    int i = blockIdx.x * 1024 + t;
    int lane = t & 63, w = t >> 6;
    int v = (i < NN) ? cnt[i] : 0;
    int sv = v;
    #pragma unroll
    for (int off = 1; off < 64; off <<= 1) {
        int u = __shfl_up(sv, off);
        if (lane >= off) sv += u;
    }
    if (lane == 63) wsum[w] = sv;
    __syncthreads();
    int woff = 0;
    #pragma unroll
    for (int j = 0; j < 16; ++j) woff += (j < w) ? wsum[j] : 0;
    if (i < NN) rp[i + 1] = sv + woff;
    if (t == 1023) bsum[blockIdx.x] = sv + woff;
}

__global__ __launch_bounds__(128) void scanB_kernel(const int* __restrict__ bsum,
                                                    int* __restrict__ boff) {
    __shared__ int wsum[2];
    int t = threadIdx.x;
    int lane = t & 63, w = t >> 6;
    int v = (t < SCANB) ? bsum[t] : 0;
    int sv = v;
    #pragma unroll
    for (int off = 1; off < 64; off <<= 1) {
        int u = __shfl_up(sv, off);
        if (lane >= off) sv += u;
    }
    if (lane == 63) wsum[w] = sv;
    __syncthreads();
    int woff = (w == 1) ? wsum[0] : 0;
    if (t < SCANB) boff[t] = sv + woff - v;   // exclusive
}

__global__ __launch_bounds__(256) void scanC_kernel(int* __restrict__ rp,
                                                    const int* __restrict__ boff) {
    int i = blockIdx.x * 256 + threadIdx.x;
    if (i == 0) rp[0] = 0;
    if (i < NN) rp[i + 1] += boff[i >> 10];
}

__global__ void place_kernel(const int* __restrict__ src, const int* __restrict__ dst,
                             const int* __restrict__ et, const float* __restrict__ rm,
                             const int* __restrict__ rp, int* __restrict__ fill,
                             int* __restrict__ csr_s, float* __restrict__ csr_w) {
    int e = blockIdx.x * 256 + threadIdx.x;
    if (e < NE) {
        int d = dst[e];
        int pos = rp[d] + atomicAdd(&fill[d], 1);
        csr_s[pos] = src[e];
        csr_w[pos] = rm[et[e] - 1];
    }
}

// ---------------------------------------------------------------- embedding gather → bf16 row-major
__global__ void embed_kernel(const int* __restrict__ ids, const float* __restrict__ tab,
                             ush_t* __restrict__ x) {
    int tid = blockIdx.x * 256 + threadIdx.x;   // NPAD*16
    int n = tid >> 4, c = tid & 15;
    if (n >= NPAD) return;
    ushort8_t h;
    if (n < NN) {
        const float4* srcp = (const float4*)(tab + (size_t)(ids[n] + 1) * DD + c * 8);
        float4 v0 = srcp[0], v1 = srcp[1];
        h[0] = f2bf(v0.x); h[1] = f2bf(v0.y); h[2] = f2bf(v0.z); h[3] = f2bf(v0.w);
        h[4] = f2bf(v1.x); h[5] = f2bf(v1.y); h[6] = f2bf(v1.z); h[7] = f2bf(v1.w);
    } else {
        #pragma unroll
        for (int e = 0; e < 8; ++e) h[e] = 0;
    }
    *(ushort8_t*)(x + (size_t)n * DD + c * 8) = h;
}

// ---------------------------------------------------------------- weight prep: Whh gates → WB mats 0..2
__global__ void wprep_kernel(const float* __restrict__ Whh, ush_t* __restrict__ WB) {
    int idx = blockIdx.x * 256 + threadIdx.x;   // 3*16384
    int mat = idx >> 14;
    int rem = idx & 16383;
    int col = rem & 127, kk = rem >> 7;
    float w = Whh[((size_t)mat * 128 + col) * 128 + kk];
    int chunk = kk >> 5, klo = kk & 31;
    int inoff = ((col >> 4) * 4 + (klo >> 3)) * 128 + (col & 15) * 8 + (klo & 7);
    WB[(size_t)(mat * 4 + chunk) * 4096 + inoff] = f2bf(w);
}

// ---------------------------------------------------------------- combined weights: C[l,g] = W_l @ Wih_g^T
__global__ __launch_bounds__(256) void cprep_kernel(const float* __restrict__ Wih,
                                                    const float* __restrict__ G,
                                                    ush_t* __restrict__ WB) {
    __shared__ float sW[16 * 128];
    int b = blockIdx.x;                 // 96 = 12 mats * 8 rowgroups
    int mat = b >> 3, rg = b & 7;
    int l = mat / 3, g = mat % 3;
    int k0 = rg * 16;
    int t = threadIdx.x;
    #pragma unroll
    for (int it = 0; it < 8; ++it) {
        int idx = it * 256 + t;
        sW[idx] = G[(size_t)l * 16384 + (size_t)(k0 + (idx >> 7)) * 128 + (idx & 127)];
    }
    __syncthreads();
    int col = t & 127, kh = t >> 7;
    float acc[8];
    #pragma unroll
    for (int e = 0; e < 8; ++e) acc[e] = 0.f;
    const float* wr = Wih + (size_t)(g * 128 + col) * 128;
    for (int j = 0; j < 128; ++j) {
        float wv = wr[j];
        #pragma unroll
        for (int e = 0; e < 8; ++e) acc[e] += sW[(kh * 8 + e) * 128 + j] * wv;
    }
    int M = 3 + l * 3 + g;
    #pragma unroll
    for (int e = 0; e < 8; ++e) {
        int k = k0 + kh * 8 + e;
        int chunk = k >> 5, klo = k & 31;
        int inoff = ((col >> 4) * 4 + (klo >> 3)) * 128 + (col & 15) * 8 + (klo & 7);
        WB[(size_t)(M * 4 + chunk) * 4096 + inoff] = f2bf(acc[e]);
    }
}

// ---------------------------------------------------------------- CSR gather: g = sum ew*x[src]
// reads row-major bf16 x (256 B/edge), writes g frag-order plane
__global__ __launch_bounds__(512) void agg_kernel(const ush_t* __restrict__ x,
                                                  const int* __restrict__ rp,
                                                  const int* __restrict__ csr_s,
                                                  const float* __restrict__ csr_w,
                                                  ush_t* __restrict__ gH) {
    int t = threadIdx.x;
    int grp = t >> 5, c = t & 31;
    int n = blockIdx.x * 16 + grp;
    if (n >= NPAD) return;
    int nout = ((n >> 7) << 14) + ((c >> 3) << 12) + (((n >> 4) & 7) << 9)
             + (((c >> 1) & 3) << 7) + ((n & 15) << 3) + ((c & 1) << 2);
    if (n >= NN) {
        *(ushort4*)(gH + nout) = make_ushort4(0, 0, 0, 0);
        return;
    }
    int e0 = rp[n], e1 = rp[n + 1];
    float4 acc = make_float4(0.f, 0.f, 0.f, 0.f);
    int e = e0;
    for (; e + 1 < e1; e += 2) {
        float w0 = csr_w[e], w1 = csr_w[e + 1];
        int s0 = csr_s[e], s1 = csr_s[e + 1];
        ushort4 p0 = *(const ushort4*)(x + (size_t)s0 * DD + c * 4);
        ushort4 p1 = *(const ushort4*)(x + (size_t)s1 * DD + c * 4);
        acc.x += w0 * bf2f(p0.x) + w1 * bf2f(p1.x);
        acc.y += w0 * bf2f(p0.y) + w1 * bf2f(p1.y);
        acc.z += w0 * bf2f(p0.z) + w1 * bf2f(p1.z);
        acc.w += w0 * bf2f(p0.w) + w1 * bf2f(p1.w);
    }
    if (e < e1) {
        float w0 = csr_w[e];
        int s0 = csr_s[e];
        ushort4 p0 = *(const ushort4*)(x + (size_t)s0 * DD + c * 4);
        acc.x += w0 * bf2f(p0.x);
        acc.y += w0 * bf2f(p0.y);
        acc.z += w0 * bf2f(p0.z);
        acc.w += w0 * bf2f(p0.w);
    }
    ushort4 oh;
    oh.x = f2bf(acc.x); oh.y = f2bf(acc.y); oh.z = f2bf(acc.z); oh.w = f2bf(acc.w);
    *(ushort4*)(gH + nout) = oh;
}

// ---------------------------------------------------------------- GRU layer kernel
// stage x tile → LDS; pass-0 x@Whh^T (A from LDS), pass-1 g@C_l (A from global frag plane);
// gates in LDS; row-major write (layers 0-2) or fused pooling (layer 3)
__global__ __launch_bounds__(256, 4) void gru_kernel(const ush_t* __restrict__ xin,
                                                     const ush_t* __restrict__ gH,
                                                     ush_t* __restrict__ xout,
                                                     const ush_t* __restrict__ WB,
                                                     const float* __restrict__ bih,
                                                     const float* __restrict__ bhh,
                                                     int layer, int is_last,
                                                     const float* __restrict__ gw,
                                                     const float* __restrict__ gb,
                                                     float* __restrict__ accum,
                                                     float* __restrict__ den) {
    __shared__ ush_t sX[64 * 136];
    __shared__ float pl[64];
    __shared__ float sT[128];
    int t = threadIdx.x;
    int tb = blockIdx.x;
    int n0 = tb * 64;
    // --- stage x tile (row-major, padded pitch)
    #pragma unroll
    for (int it = 0; it < 4; ++it) {
        int idx = it * 256 + t;          // 1024 chunks of 16B
        int row = idx >> 4, seg = idx & 15;
        ushort8_t v = *(const ushort8_t*)(xin + (size_t)(n0 + row) * DD + seg * 8);
        *(ushort8_t*)(sX + row * 136 + seg * 8) = v;
    }
    __syncthreads();
    // --- MFMA
    int l = t & 63, w = t >> 6;
    int lg = l >> 4, lc = l & 15;
    floatx4 accR[4][2], accZ[4][2], accN[4][2], accI[4][2];
    #pragma unroll
    for (int i = 0; i < 4; ++i)
        #pragma unroll
        for (int j = 0; j < 2; ++j) {
            accR[i][j] = (floatx4)0.f; accZ[i][j] = (floatx4)0.f;
            accN[i][j] = (floatx4)0.f; accI[i][j] = (floatx4)0.f;
        }
    int gbase = (tb >> 1) * 16384 + (tb & 1) * 2048 + lg * 128 + lc * 8;
    #pragma unroll
    for (int pass = 0; pass < 2; ++pass) {
        int matbase = pass ? (3 + layer * 3) : 0;
        #pragma unroll
        for (int kc = 0; kc < 4; ++kc) {
            short8 aHf[4];
            if (pass == 0) {
                #pragma unroll
                for (int i = 0; i < 4; ++i)
                    aHf[i] = *(const short8*)(sX + (i * 16 + lc) * 136 + kc * 32 + lg * 8);
            } else {
                #pragma unroll
                for (int i = 0; i < 4; ++i)
                    aHf[i] = *(const short8*)(gH + gbase + kc * 4096 + i * 512);
            }
            #pragma unroll
            for (int m3 = 0; m3 < 3; ++m3) {
                floatx4 (*accp)[2] = (m3 == 0) ? accR : (m3 == 1) ? accZ : (pass ? accI : accN);
                const ush_t* wb = WB + (size_t)((matbase + m3) * 4 + kc) * 4096;
                #pragma unroll
                for (int j = 0; j < 2; ++j) {
                    int boff = (((w * 2 + j) * 4 + lg) * 16 + lc) * 8;
                    short8 bH = *(const short8*)(wb + boff);
                    #pragma unroll
                    for (int i = 0; i < 4; ++i)
                        accp[i][j] = __builtin_amdgcn_mfma_f32_16x16x32_bf16(aHf[i], bH, accp[i][j], 0, 0, 0);
                }
            }
        }
    }
    __syncthreads();   // all sX A-frag reads done before overwrite
    // --- gates + blend, in-place into sX
    #pragma unroll
    for (int j = 0; j < 2; ++j) {
        int col = w * 32 + j * 16 + lc;
        float bIr = bih[col],       bHr = bhh[col];
        float bIz = bih[128 + col], bHz = bhh[128 + col];
        float bIn = bih[256 + col], bHn = bhh[256 + col];
        #pragma unroll
        for (int i = 0; i < 4; ++i)
            #pragma unroll
            for (int r = 0; r < 4; ++r) {
                int row = i * 16 + lg * 4 + r;
                float v = 0.f;
                if (n0 + row < NN) {
                    float rr = sigf(accR[i][j][r] + bIr + bHr);
                    float zz = sigf(accZ[i][j][r] + bIz + bHz);
                    float nn = tanhf_fast(accI[i][j][r] + bIn + rr * (accN[i][j][r] + bHn));
                    float h = bf2f(sX[row * 136 + col]);
                    v = (1.0f - zz) * nn + zz * h;
                }
                sX[row * 136 + col] = f2bf(v);
            }
    }
    __syncthreads();
    if (!is_last) {
        // --- coalesced row-major write-out
        #pragma unroll
        for (int it = 0; it < 4; ++it) {
            int idx = it * 256 + t;
            int row = idx >> 4, seg = idx & 15;
            ushort8_t v = *(const ushort8_t*)(sX + row * 136 + seg * 8);
            *(ushort8_t*)(xout + (size_t)(n0 + row) * DD + seg * 8) = v;
        }
    } else {
        // --- fused global-attention pooling (replicated accumulators)
        int row = t >> 2, q = t & 3;
        float s = 0.f;
        #pragma unroll
        for (int e = 0; e < 32; ++e)
            s += bf2f(sX[row * 136 + q * 32 + e]) * gw[q * 32 + e];
        s += __shfl_xor(s, 1);
        s += __shfl_xor(s, 2);
        if (q == 0)
            pl[row] = (n0 + row < NN) ? __expf(sigf(s + gb[0])) : 0.f;
        __syncthreads();
        int cc = t & 127, half = t >> 7;
        float acc = 0.f;
        #pragma unroll
        for (int r = 0; r < 32; ++r)
            acc += pl[half * 32 + r] * bf2f(sX[(half * 32 + r) * 136 + cc]);
        if (half == 0) sT[cc] = acc;
        __syncthreads();
        if (half == 1) atomicAdd(&accum[(tb & 63) * 128 + cc], acc + sT[cc]);
        if (t < 64) {
            float v = pl[t];
            #pragma unroll
            for (int o = 32; o > 0; o >>= 1) v += __shfl_xor(v, o);
            if (t == 0) atomicAdd(&den[tb & 63], v);
        }
    }
}

__global__ void finalize_kernel(const float* __restrict__ accum, const float* __restrict__ den,
                                float* __restrict__ out) {
    __shared__ float dsum;
    int d = threadIdx.x;   // 128
    float s = 0.f;
    for (int rep = 0; rep < 64; ++rep) s += accum[rep * 128 + d];
    if (d == 0) {
        float ds = 0.f;
        for (int rep = 0; rep < 64; ++rep) ds += den[rep];
        dsum = ds;
    }
    __syncthreads();
    out[d] = s / dsum;
}

// ---------------------------------------------------------------- launch
extern "C" void kernel_launch(void* const* d_in, const int* in_sizes, int n_in,
                              void* d_out, int out_size, void* d_ws, size_t ws_size,
                              hipStream_t stream) {
    const int*   node_ids    = (const int*)d_in[0];
    const int*   edges       = (const int*)d_in[1];
    const int*   edge_types  = (const int*)d_in[2];
    const float* embed_table = (const float*)d_in[3];
    const float* edge_tab    = (const float*)d_in[4];
    const float* ggnn_w      = (const float*)d_in[5];
    const float* Wih         = (const float*)d_in[6];
    const float* Whh         = (const float*)d_in[7];
    const float* bih         = (const float*)d_in[8];
    const float* bhh         = (const float*)d_in[9];
    const float* gate_w      = (const float*)d_in[10];
    const float* gate_b      = (const float*)d_in[11];
    float* out = (float*)d_out;

    const size_t PL = (size_t)NPAD * DD;
    ush_t* wsb  = (ush_t*)d_ws;
    ush_t* xA   = wsb;
    ush_t* xB   = xA + PL;
    ush_t* gH   = xB + PL;          // frag plane
    ush_t* WB   = gH + PL;          // 15 mats * 4 chunks * 4096
    float* csr_w = (float*)(WB + 15 * 4 * 4096);
    float* accum = csr_w + NE;      // 64 * 128
    float* den   = accum + 64 * 128; // 64
    float* rm    = den + 64;        // 7(+1)
    int*   rp    = (int*)(rm + 8);  // N+1
    int*   fill  = rp + NN + 1;     // N
    int*   csr_s = fill + NN;       // E
    int*   bsum  = csr_s + NE;      // 128
    int*   boff  = bsum + 128;      // 128

    const int* src = edges;
    const int* dst = edges + NE;

    // one-time prep
    rowmean_kernel<<<7, 128, 0, stream>>>(edge_tab, rm);
    hipMemsetAsync(fill, 0, NN * sizeof(int), stream);
    hist_kernel<<<(NE + 255) / 256, 256, 0, stream>>>(dst, fill);
    scanA_kernel<<<SCANB, 1024, 0, stream>>>(fill, rp, bsum);
    scanB_kernel<<<1, 128, 0, stream>>>(bsum, boff);
    scanC_kernel<<<(NN + 255) / 256, 256, 0, stream>>>(rp, boff);
    hipMemsetAsync(fill, 0, NN * sizeof(int), stream);
    place_kernel<<<(NE + 255) / 256, 256, 0, stream>>>(src, dst, edge_types, rm, rp, fill,
                                                       csr_s, csr_w);
    embed_kernel<<<NPAD * 16 / 256, 256, 0, stream>>>(node_ids, embed_table, xA);
    wprep_kernel<<<192, 256, 0, stream>>>(Whh, WB);
    cprep_kernel<<<96, 256, 0, stream>>>(Wih, ggnn_w, WB);
    hipMemsetAsync(accum, 0, (64 * 128 + 64) * sizeof(float), stream);

    // 4 layers: standalone high-occupancy gather + gru
    ush_t* x = xA;
    ush_t* xo = xB;
    for (int layer = 0; layer < 4; ++layer) {
        agg_kernel<<<(NPAD + 15) / 16, 512, 0, stream>>>(x, rp, csr_s, csr_w, gH);
        gru_kernel<<<NT2, 256, 0, stream>>>(x, gH, xo, WB, bih, bhh,
                                            layer, layer == 3 ? 1 : 0,
                                            gate_w, gate_b, accum, den);
        ush_t* tmp = x; x = xo; xo = tmp;
    }

    finalize_kernel<<<1, 128, 0, stream>>>(accum, den, out);
}

// Round 13
// 566.778 us; speedup vs baseline: 1.4132x; 1.3913x over previous
//
#include <hip/hip_runtime.h>
#include <math.h>

#define NN 100000
#define NPAD 100096
#define NT2 1564      // NPAD / 64 (gru blocks)
#define NE 800000
#define DD 128
#define SCANB 98      // ceil(NN/1024)

typedef __attribute__((ext_vector_type(8))) short short8;
typedef __attribute__((ext_vector_type(4))) float floatx4;
typedef unsigned short ush_t;
typedef __attribute__((ext_vector_type(8))) unsigned short ushort8_t;

__device__ __forceinline__ ush_t f2bf(float f) {
    unsigned u = __float_as_uint(f);
    return (ush_t)((u + 0x7fffu + ((u >> 16) & 1u)) >> 16);
}
__device__ __forceinline__ float bf2f(ush_t h) {
    return __uint_as_float((unsigned)h << 16);
}
__device__ __forceinline__ float sigf(float x) {
    return __builtin_amdgcn_rcpf(1.0f + __expf(-x));
}
__device__ __forceinline__ float tanhf_fast(float x) {
    x = fminf(fmaxf(x, -20.0f), 20.0f);
    float e = __expf(2.0f * x);
    return 1.0f - 2.0f * __builtin_amdgcn_rcpf(e + 1.0f);
}

// ---------------------------------------------------------------- row means of edge-type table
__global__ void rowmean_kernel(const float* __restrict__ tab, float* __restrict__ rm) {
    int r = blockIdx.x;
    int t = threadIdx.x;
    float v = tab[r * DD + t];
    #pragma unroll
    for (int o = 32; o > 0; o >>= 1) v += __shfl_xor(v, o);
    __shared__ float red[2];
    if ((t & 63) == 0) red[t >> 6] = v;
    __syncthreads();
    if (t == 0) rm[r] = (red[0] + red[1]) * (1.0f / DD);
}

// ---------------------------------------------------------------- CSR build
__global__ void hist_kernel(const int* __restrict__ dst, int* __restrict__ fill) {
    int e = blockIdx.x * 256 + threadIdx.x;
    if (e < NE) atomicAdd(&fill[dst[e]], 1);
}

__global__ __launch_bounds__(1024) void scanA_kernel(const int* __restrict__ cnt,
                                                     int* __restrict__ rp,
                                                     int* __restrict__ bsum) {
    __shared__ int wsum[16];
    int t = threadIdx.x;
    int i = blockIdx.x * 1024 + t;
    int lane = t & 63, w = t >> 6;
    int v = (i < NN) ? cnt[i] : 0;
    int sv = v;
    #pragma unroll
    for (int off = 1; off < 64; off <<= 1) {
        int u = __shfl_up(sv, off);
        if (lane >= off) sv += u;
    }
    if (lane == 63) wsum[w] = sv;
    __syncthreads();
    int woff = 0;
    #pragma unroll
    for (int j = 0; j < 16; ++j) woff += (j < w) ? wsum[j] : 0;
    if (i < NN) rp[i + 1] = sv + woff;
    if (t == 1023) bsum[blockIdx.x] = sv + woff;
}

__global__ __launch_bounds__(128) void scanB_kernel(const int* __restrict__ bsum,
                                                    int* __restrict__ boff) {
    __shared__ int wsum[2];
    int t = threadIdx.x;
    int lane = t & 63, w = t >> 6;
    int v = (t < SCANB) ? bsum[t] : 0;
    int sv = v;
    #pragma unroll
    for (int off = 1; off < 64; off <<= 1) {
        int u = __shfl_up(sv, off);
        if (lane >= off) sv += u;
    }
    if (lane == 63) wsum[w] = sv;
    __syncthreads();
    int woff = (w == 1) ? wsum[0] : 0;
    if (t < SCANB) boff[t] = sv + woff - v;   // exclusive
}

__global__ __launch_bounds__(256) void scanC_kernel(int* __restrict__ rp,
                                                    const int* __restrict__ boff) {
    int i = blockIdx.x * 256 + threadIdx.x;
    if (i == 0) rp[0] = 0;
    if (i < NN) rp[i + 1] += boff[i >> 10];
}

__global__ void place_kernel(const int* __restrict__ src, const int* __restrict__ dst,
                             const int* __restrict__ et, const float* __restrict__ rm,
                             const int* __restrict__ rp, int* __restrict__ fill,
                             int* __restrict__ csr_s, float* __restrict__ csr_w) {
    int e = blockIdx.x * 256 + threadIdx.x;
    if (e < NE) {
        int d = dst[e];
        int pos = rp[d] + atomicAdd(&fill[d], 1);
        csr_s[pos] = src[e];
        csr_w[pos] = rm[et[e] - 1];
    }
}

// ---------------------------------------------------------------- embedding gather → bf16 row-major
__global__ void embed_kernel(const int* __restrict__ ids, const float* __restrict__ tab,
                             ush_t* __restrict__ x) {
    int tid = blockIdx.x * 256 + threadIdx.x;   // NPAD*16
    int n = tid >> 4, c = tid & 15;
    if (n >= NPAD) return;
    ushort8_t h;
    if (n < NN) {
        const float4* srcp = (const float4*)(tab + (size_t)(ids[n] + 1) * DD + c * 8);
        float4 v0 = srcp[0], v1 = srcp[1];
        h[0] = f2bf(v0.x); h[1] = f2bf(v0.y); h[2] = f2bf(v0.z); h[3] = f2bf(v0.w);
        h[4] = f2bf(v1.x); h[5] = f2bf(v1.y); h[6] = f2bf(v1.z); h[7] = f2bf(v1.w);
    } else {
        #pragma unroll
        for (int e = 0; e < 8; ++e) h[e] = 0;
    }
    *(ushort8_t*)(x + (size_t)n * DD + c * 8) = h;
}

// ---------------------------------------------------------------- weight prep: Whh gates → WB mats 0..2
__global__ void wprep_kernel(const float* __restrict__ Whh, ush_t* __restrict__ WB) {
    int idx = blockIdx.x * 256 + threadIdx.x;   // 3*16384
    int mat = idx >> 14;
    int rem = idx & 16383;
    int col = rem & 127, kk = rem >> 7;
    float w = Whh[((size_t)mat * 128 + col) * 128 + kk];
    int chunk = kk >> 5, klo = kk & 31;
    int inoff = ((col >> 4) * 4 + (klo >> 3)) * 128 + (col & 15) * 8 + (klo & 7);
    WB[(size_t)(mat * 4 + chunk) * 4096 + inoff] = f2bf(w);
}

// ---------------------------------------------------------------- combined weights: C[l,g] = W_l @ Wih_g^T
__global__ __launch_bounds__(256) void cprep_kernel(const float* __restrict__ Wih,
                                                    const float* __restrict__ G,
                                                    ush_t* __restrict__ WB) {
    __shared__ float sW[16 * 128];
    int b = blockIdx.x;                 // 96 = 12 mats * 8 rowgroups
    int mat = b >> 3, rg = b & 7;
    int l = mat / 3, g = mat % 3;
    int k0 = rg * 16;
    int t = threadIdx.x;
    #pragma unroll
    for (int it = 0; it < 8; ++it) {
        int idx = it * 256 + t;
        sW[idx] = G[(size_t)l * 16384 + (size_t)(k0 + (idx >> 7)) * 128 + (idx & 127)];
    }
    __syncthreads();
    int col = t & 127, kh = t >> 7;
    float acc[8];
    #pragma unroll
    for (int e = 0; e < 8; ++e) acc[e] = 0.f;
    const float* wr = Wih + (size_t)(g * 128 + col) * 128;
    for (int j = 0; j < 128; ++j) {
        float wv = wr[j];
        #pragma unroll
        for (int e = 0; e < 8; ++e) acc[e] += sW[(kh * 8 + e) * 128 + j] * wv;
    }
    int M = 3 + l * 3 + g;
    #pragma unroll
    for (int e = 0; e < 8; ++e) {
        int k = k0 + kh * 8 + e;
        int chunk = k >> 5, klo = k & 31;
        int inoff = ((col >> 4) * 4 + (klo >> 3)) * 128 + (col & 15) * 8 + (klo & 7);
        WB[(size_t)(M * 4 + chunk) * 4096 + inoff] = f2bf(acc[e]);
    }
}

// ---------------------------------------------------------------- CSR gather: g = sum ew*x[src]
__global__ __launch_bounds__(512) void agg_kernel(const ush_t* __restrict__ x,
                                                  const int* __restrict__ rp,
                                                  const int* __restrict__ csr_s,
                                                  const float* __restrict__ csr_w,
                                                  ush_t* __restrict__ gH) {
    int t = threadIdx.x;
    int grp = t >> 5, c = t & 31;
    int n = blockIdx.x * 16 + grp;
    if (n >= NPAD) return;
    int nout = ((n >> 7) << 14) + ((c >> 3) << 12) + (((n >> 4) & 7) << 9)
             + (((c >> 1) & 3) << 7) + ((n & 15) << 3) + ((c & 1) << 2);
    if (n >= NN) {
        *(ushort4*)(gH + nout) = make_ushort4(0, 0, 0, 0);
        return;
    }
    int e0 = rp[n], e1 = rp[n + 1];
    float4 acc = make_float4(0.f, 0.f, 0.f, 0.f);
    int e = e0;
    for (; e + 1 < e1; e += 2) {
        float w0 = csr_w[e], w1 = csr_w[e + 1];
        int s0 = csr_s[e], s1 = csr_s[e + 1];
        ushort4 p0 = *(const ushort4*)(x + (size_t)s0 * DD + c * 4);
        ushort4 p1 = *(const ushort4*)(x + (size_t)s1 * DD + c * 4);
        acc.x += w0 * bf2f(p0.x) + w1 * bf2f(p1.x);
        acc.y += w0 * bf2f(p0.y) + w1 * bf2f(p1.y);
        acc.z += w0 * bf2f(p0.z) + w1 * bf2f(p1.z);
        acc.w += w0 * bf2f(p0.w) + w1 * bf2f(p1.w);
    }
    if (e < e1) {
        float w0 = csr_w[e];
        int s0 = csr_s[e];
        ushort4 p0 = *(const ushort4*)(x + (size_t)s0 * DD + c * 4);
        acc.x += w0 * bf2f(p0.x);
        acc.y += w0 * bf2f(p0.y);
        acc.z += w0 * bf2f(p0.z);
        acc.w += w0 * bf2f(p0.w);
    }
    ushort4 oh;
    oh.x = f2bf(acc.x); oh.y = f2bf(acc.y); oh.z = f2bf(acc.z); oh.w = f2bf(acc.w);
    *(ushort4*)(gH + nout) = oh;
}

// ---------------------------------------------------------------- GRU layer kernel
// launch_bounds (256,2): 128 accumulator AGPRs + ~60 VGPRs must fit in the
// per-wave budget — 4 waves/SIMD forces a 128-reg cap and spills 200+ MB to
// scratch (measured R12). DO NOT raise the second argument.
__global__ __launch_bounds__(256, 2) void gru_kernel(const ush_t* __restrict__ xin,
                                                     const ush_t* __restrict__ gH,
                                                     ush_t* __restrict__ xout,
                                                     const ush_t* __restrict__ WB,
                                                     const float* __restrict__ bih,
                                                     const float* __restrict__ bhh,
                                                     int layer, int is_last,
                                                     const float* __restrict__ gw,
                                                     const float* __restrict__ gb,
                                                     float* __restrict__ accum,
                                                     float* __restrict__ den) {
    __shared__ ush_t sX[64 * 136];
    __shared__ float pl[64];
    __shared__ float sT[128];
    int t = threadIdx.x;
    int tb = blockIdx.x;
    int n0 = tb * 64;
    // --- stage x tile (row-major, padded pitch)
    #pragma unroll
    for (int it = 0; it < 4; ++it) {
        int idx = it * 256 + t;          // 1024 chunks of 16B
        int row = idx >> 4, seg = idx & 15;
        ushort8_t v = *(const ushort8_t*)(xin + (size_t)(n0 + row) * DD + seg * 8);
        *(ushort8_t*)(sX + row * 136 + seg * 8) = v;
    }
    __syncthreads();
    // --- MFMA
    int l = t & 63, w = t >> 6;
    int lg = l >> 4, lc = l & 15;
    floatx4 accR[4][2], accZ[4][2], accN[4][2], accI[4][2];
    #pragma unroll
    for (int i = 0; i < 4; ++i)
        #pragma unroll
        for (int j = 0; j < 2; ++j) {
            accR[i][j] = (floatx4)0.f; accZ[i][j] = (floatx4)0.f;
            accN[i][j] = (floatx4)0.f; accI[i][j] = (floatx4)0.f;
        }
    int gbase = (tb >> 1) * 16384 + (tb & 1) * 2048 + lg * 128 + lc * 8;
    #pragma unroll
    for (int pass = 0; pass < 2; ++pass) {
        int matbase = pass ? (3 + layer * 3) : 0;
        #pragma unroll
        for (int kc = 0; kc < 4; ++kc) {
            short8 aHf[4];
            if (pass == 0) {
                #pragma unroll
                for (int i = 0; i < 4; ++i)
                    aHf[i] = *(const short8*)(sX + (i * 16 + lc) * 136 + kc * 32 + lg * 8);
            } else {
                #pragma unroll
                for (int i = 0; i < 4; ++i)
                    aHf[i] = *(const short8*)(gH + gbase + kc * 4096 + i * 512);
            }
            #pragma unroll
            for (int m3 = 0; m3 < 3; ++m3) {
                floatx4 (*accp)[2] = (m3 == 0) ? accR : (m3 == 1) ? accZ : (pass ? accI : accN);
                const ush_t* wb = WB + (size_t)((matbase + m3) * 4 + kc) * 4096;
                #pragma unroll
                for (int j = 0; j < 2; ++j) {
                    int boff = (((w * 2 + j) * 4 + lg) * 16 + lc) * 8;
                    short8 bH = *(const short8*)(wb + boff);
                    #pragma unroll
                    for (int i = 0; i < 4; ++i)
                        accp[i][j] = __builtin_amdgcn_mfma_f32_16x16x32_bf16(aHf[i], bH, accp[i][j], 0, 0, 0);
                }
            }
        }
    }
    __syncthreads();   // all sX A-frag reads done before overwrite
    // --- gates + blend, in-place into sX
    #pragma unroll
    for (int j = 0; j < 2; ++j) {
        int col = w * 32 + j * 16 + lc;
        float bIr = bih[col],       bHr = bhh[col];
        float bIz = bih[128 + col], bHz = bhh[128 + col];
        float bIn = bih[256 + col], bHn = bhh[256 + col];
        #pragma unroll
        for (int i = 0; i < 4; ++i)
            #pragma unroll
            for (int r = 0; r < 4; ++r) {
                int row = i * 16 + lg * 4 + r;
                float v = 0.f;
                if (n0 + row < NN) {
                    float rr = sigf(accR[i][j][r] + bIr + bHr);
                    float zz = sigf(accZ[i][j][r] + bIz + bHz);
                    float nn = tanhf_fast(accI[i][j][r] + bIn + rr * (accN[i][j][r] + bHn));
                    float h = bf2f(sX[row * 136 + col]);
                    v = (1.0f - zz) * nn + zz * h;
                }
                sX[row * 136 + col] = f2bf(v);
            }
    }
    __syncthreads();
    if (!is_last) {
        // --- coalesced row-major write-out
        #pragma unroll
        for (int it = 0; it < 4; ++it) {
            int idx = it * 256 + t;
            int row = idx >> 4, seg = idx & 15;
            ushort8_t v = *(const ushort8_t*)(sX + row * 136 + seg * 8);
            *(ushort8_t*)(xout + (size_t)(n0 + row) * DD + seg * 8) = v;
        }
    } else {
        // --- fused global-attention pooling (replicated accumulators)
        int row = t >> 2, q = t & 3;
        float s = 0.f;
        #pragma unroll
        for (int e = 0; e < 32; ++e)
            s += bf2f(sX[row * 136 + q * 32 + e]) * gw[q * 32 + e];
        s += __shfl_xor(s, 1);
        s += __shfl_xor(s, 2);
        if (q == 0)
            pl[row] = (n0 + row < NN) ? __expf(sigf(s + gb[0])) : 0.f;
        __syncthreads();
        int cc = t & 127, half = t >> 7;
        float acc = 0.f;
        #pragma unroll
        for (int r = 0; r < 32; ++r)
            acc += pl[half * 32 + r] * bf2f(sX[(half * 32 + r) * 136 + cc]);
        if (half == 0) sT[cc] = acc;
        __syncthreads();
        if (half == 1) atomicAdd(&accum[(tb & 63) * 128 + cc], acc + sT[cc]);
        if (t < 64) {
            float v = pl[t];
            #pragma unroll
            for (int o = 32; o > 0; o >>= 1) v += __shfl_xor(v, o);
            if (t == 0) atomicAdd(&den[tb & 63], v);
        }
    }
}

__global__ void finalize_kernel(const float* __restrict__ accum, const float* __restrict__ den,
                                float* __restrict__ out) {
    __shared__ float dsum;
    int d = threadIdx.x;   // 128
    float s = 0.f;
    for (int rep = 0; rep < 64; ++rep) s += accum[rep * 128 + d];
    if (d == 0) {
        float ds = 0.f;
        for (int rep = 0; rep < 64; ++rep) ds += den[rep];
        dsum = ds;
    }
    __syncthreads();
    out[d] = s / dsum;
}

// ---------------------------------------------------------------- launch
extern "C" void kernel_launch(void* const* d_in, const int* in_sizes, int n_in,
                              void* d_out, int out_size, void* d_ws, size_t ws_size,
                              hipStream_t stream) {
    const int*   node_ids    = (const int*)d_in[0];
    const int*   edges       = (const int*)d_in[1];
    const int*   edge_types  = (const int*)d_in[2];
    const float* embed_table = (const float*)d_in[3];
    const float* edge_tab    = (const float*)d_in[4];
    const float* ggnn_w      = (const float*)d_in[5];
    const float* Wih         = (const float*)d_in[6];
    const float* Whh         = (const float*)d_in[7];
    const float* bih         = (const float*)d_in[8];
    const float* bhh         = (const float*)d_in[9];
    const float* gate_w      = (const float*)d_in[10];
    const float* gate_b      = (const float*)d_in[11];
    float* out = (float*)d_out;

    const size_t PL = (size_t)NPAD * DD;
    ush_t* wsb  = (ush_t*)d_ws;
    ush_t* xA   = wsb;
    ush_t* xB   = xA + PL;
    ush_t* gH   = xB + PL;          // frag plane
    ush_t* WB   = gH + PL;          // 15 mats * 4 chunks * 4096
    float* csr_w = (float*)(WB + 15 * 4 * 4096);
    float* accum = csr_w + NE;      // 64 * 128
    float* den   = accum + 64 * 128; // 64
    float* rm    = den + 64;        // 7(+1)
    int*   rp    = (int*)(rm + 8);  // N+1
    int*   fill  = rp + NN + 1;     // N
    int*   csr_s = fill + NN;       // E
    int*   bsum  = csr_s + NE;      // 128
    int*   boff  = bsum + 128;      // 128

    const int* src = edges;
    const int* dst = edges + NE;

    // one-time prep
    rowmean_kernel<<<7, 128, 0, stream>>>(edge_tab, rm);
    hipMemsetAsync(fill, 0, NN * sizeof(int), stream);
    hist_kernel<<<(NE + 255) / 256, 256, 0, stream>>>(dst, fill);
    scanA_kernel<<<SCANB, 1024, 0, stream>>>(fill, rp, bsum);
    scanB_kernel<<<1, 128, 0, stream>>>(bsum, boff);
    scanC_kernel<<<(NN + 255) / 256, 256, 0, stream>>>(rp, boff);
    hipMemsetAsync(fill, 0, NN * sizeof(int), stream);
    place_kernel<<<(NE + 255) / 256, 256, 0, stream>>>(src, dst, edge_types, rm, rp, fill,
                                                       csr_s, csr_w);
    embed_kernel<<<NPAD * 16 / 256, 256, 0, stream>>>(node_ids, embed_table, xA);
    wprep_kernel<<<192, 256, 0, stream>>>(Whh, WB);
    cprep_kernel<<<96, 256, 0, stream>>>(Wih, ggnn_w, WB);
    hipMemsetAsync(accum, 0, (64 * 128 + 64) * sizeof(float), stream);

    // 4 layers: standalone high-occupancy gather + gru
    ush_t* x = xA;
    ush_t* xo = xB;
    for (int layer = 0; layer < 4; ++layer) {
        agg_kernel<<<(NPAD + 15) / 16, 512, 0, stream>>>(x, rp, csr_s, csr_w, gH);
        gru_kernel<<<NT2, 256, 0, stream>>>(x, gH, xo, WB, bih, bhh,
                                            layer, layer == 3 ? 1 : 0,
                                            gate_w, gate_b, accum, den);
        ush_t* tmp = x; x = xo; xo = tmp;
    }

    finalize_kernel<<<1, 128, 0, stream>>>(accum, den, out);
}

// Round 14
// 552.043 us; speedup vs baseline: 1.4509x; 1.0267x over previous
//
#include <hip/hip_runtime.h>
#include <math.h>

#define NN 100000
#define NPAD 100096
#define NT3 3128      // NPAD / 32 (gru blocks)
#define NE 800000
#define DD 128
#define SCANB 98      // ceil(NN/1024)

typedef __attribute__((ext_vector_type(8))) short short8;
typedef __attribute__((ext_vector_type(4))) float floatx4;
typedef unsigned short ush_t;
typedef __attribute__((ext_vector_type(8))) unsigned short ushort8_t;

__device__ __forceinline__ ush_t f2bf(float f) {
    unsigned u = __float_as_uint(f);
    return (ush_t)((u + 0x7fffu + ((u >> 16) & 1u)) >> 16);
}
__device__ __forceinline__ float bf2f(ush_t h) {
    return __uint_as_float((unsigned)h << 16);
}
__device__ __forceinline__ float sigf(float x) {
    return __builtin_amdgcn_rcpf(1.0f + __expf(-x));
}
__device__ __forceinline__ float tanhf_fast(float x) {
    x = fminf(fmaxf(x, -20.0f), 20.0f);
    float e = __expf(2.0f * x);
    return 1.0f - 2.0f * __builtin_amdgcn_rcpf(e + 1.0f);
}

// ---------------------------------------------------------------- row means of edge-type table
__global__ void rowmean_kernel(const float* __restrict__ tab, float* __restrict__ rm) {
    int r = blockIdx.x;
    int t = threadIdx.x;
    float v = tab[r * DD + t];
    #pragma unroll
    for (int o = 32; o > 0; o >>= 1) v += __shfl_xor(v, o);
    __shared__ float red[2];
    if ((t & 63) == 0) red[t >> 6] = v;
    __syncthreads();
    if (t == 0) rm[r] = (red[0] + red[1]) * (1.0f / DD);
}

// ---------------------------------------------------------------- CSR build
__global__ void hist_kernel(const int* __restrict__ dst, int* __restrict__ fill) {
    int e = blockIdx.x * 256 + threadIdx.x;
    if (e < NE) atomicAdd(&fill[dst[e]], 1);
}

__global__ __launch_bounds__(1024) void scanA_kernel(const int* __restrict__ cnt,
                                                     int* __restrict__ rp,
                                                     int* __restrict__ bsum) {
    __shared__ int wsum[16];
    int t = threadIdx.x;
    int i = blockIdx.x * 1024 + t;
    int lane = t & 63, w = t >> 6;
    int v = (i < NN) ? cnt[i] : 0;
    int sv = v;
    #pragma unroll
    for (int off = 1; off < 64; off <<= 1) {
        int u = __shfl_up(sv, off);
        if (lane >= off) sv += u;
    }
    if (lane == 63) wsum[w] = sv;
    __syncthreads();
    int woff = 0;
    #pragma unroll
    for (int j = 0; j < 16; ++j) woff += (j < w) ? wsum[j] : 0;
    if (i < NN) rp[i + 1] = sv + woff;
    if (t == 1023) bsum[blockIdx.x] = sv + woff;
}

__global__ __launch_bounds__(128) void scanB_kernel(const int* __restrict__ bsum,
                                                    int* __restrict__ boff) {
    __shared__ int wsum[2];
    int t = threadIdx.x;
    int lane = t & 63, w = t >> 6;
    int v = (t < SCANB) ? bsum[t] : 0;
    int sv = v;
    #pragma unroll
    for (int off = 1; off < 64; off <<= 1) {
        int u = __shfl_up(sv, off);
        if (lane >= off) sv += u;
    }
    if (lane == 63) wsum[w] = sv;
    __syncthreads();
    int woff = (w == 1) ? wsum[0] : 0;
    if (t < SCANB) boff[t] = sv + woff - v;   // exclusive
}

__global__ __launch_bounds__(256) void scanC_kernel(int* __restrict__ rp,
                                                    const int* __restrict__ boff) {
    int i = blockIdx.x * 256 + threadIdx.x;
    if (i == 0) rp[0] = 0;
    if (i < NN) rp[i + 1] += boff[i >> 10];
}

// single interleaved 8B record per edge: (src, weight-bits) — one scattered
// store instead of two (R13: two 4B streams cost 85MB of line-granular writes)
__global__ void place_kernel(const int* __restrict__ src, const int* __restrict__ dst,
                             const int* __restrict__ et, const float* __restrict__ rm,
                             const int* __restrict__ rp, int* __restrict__ fill,
                             uint2* __restrict__ csr) {
    int e = blockIdx.x * 256 + threadIdx.x;
    if (e < NE) {
        int d = dst[e];
        int pos = rp[d] + atomicAdd(&fill[d], 1);
        uint2 rec;
        rec.x = (unsigned)src[e];
        rec.y = __float_as_uint(rm[et[e] - 1]);
        csr[pos] = rec;
    }
}

// ---------------------------------------------------------------- embedding gather → bf16 row-major
__global__ void embed_kernel(const int* __restrict__ ids, const float* __restrict__ tab,
                             ush_t* __restrict__ x) {
    int tid = blockIdx.x * 256 + threadIdx.x;   // NPAD*16
    int n = tid >> 4, c = tid & 15;
    if (n >= NPAD) return;
    ushort8_t h;
    if (n < NN) {
        const float4* srcp = (const float4*)(tab + (size_t)(ids[n] + 1) * DD + c * 8);
        float4 v0 = srcp[0], v1 = srcp[1];
        h[0] = f2bf(v0.x); h[1] = f2bf(v0.y); h[2] = f2bf(v0.z); h[3] = f2bf(v0.w);
        h[4] = f2bf(v1.x); h[5] = f2bf(v1.y); h[6] = f2bf(v1.z); h[7] = f2bf(v1.w);
    } else {
        #pragma unroll
        for (int e = 0; e < 8; ++e) h[e] = 0;
    }
    *(ushort8_t*)(x + (size_t)n * DD + c * 8) = h;
}

// ---------------------------------------------------------------- weight prep: Whh gates → WB mats 0..2
__global__ void wprep_kernel(const float* __restrict__ Whh, ush_t* __restrict__ WB) {
    int idx = blockIdx.x * 256 + threadIdx.x;   // 3*16384
    int mat = idx >> 14;
    int rem = idx & 16383;
    int col = rem & 127, kk = rem >> 7;
    float w = Whh[((size_t)mat * 128 + col) * 128 + kk];
    int chunk = kk >> 5, klo = kk & 31;
    int inoff = ((col >> 4) * 4 + (klo >> 3)) * 128 + (col & 15) * 8 + (klo & 7);
    WB[(size_t)(mat * 4 + chunk) * 4096 + inoff] = f2bf(w);
}

// ---------------------------------------------------------------- combined weights: C[l,g] = W_l @ Wih_g^T
__global__ __launch_bounds__(256) void cprep_kernel(const float* __restrict__ Wih,
                                                    const float* __restrict__ G,
                                                    ush_t* __restrict__ WB) {
    __shared__ float sW[16 * 128];
    int b = blockIdx.x;                 // 96 = 12 mats * 8 rowgroups
    int mat = b >> 3, rg = b & 7;
    int l = mat / 3, g = mat % 3;
    int k0 = rg * 16;
    int t = threadIdx.x;
    #pragma unroll
    for (int it = 0; it < 8; ++it) {
        int idx = it * 256 + t;
        sW[idx] = G[(size_t)l * 16384 + (size_t)(k0 + (idx >> 7)) * 128 + (idx & 127)];
    }
    __syncthreads();
    int col = t & 127, kh = t >> 7;
    float acc[8];
    #pragma unroll
    for (int e = 0; e < 8; ++e) acc[e] = 0.f;
    const float* wr = Wih + (size_t)(g * 128 + col) * 128;
    for (int j = 0; j < 128; ++j) {
        float wv = wr[j];
        #pragma unroll
        for (int e = 0; e < 8; ++e) acc[e] += sW[(kh * 8 + e) * 128 + j] * wv;
    }
    int M = 3 + l * 3 + g;
    #pragma unroll
    for (int e = 0; e < 8; ++e) {
        int k = k0 + kh * 8 + e;
        int chunk = k >> 5, klo = k & 31;
        int inoff = ((col >> 4) * 4 + (klo >> 3)) * 128 + (col & 15) * 8 + (klo & 7);
        WB[(size_t)(M * 4 + chunk) * 4096 + inoff] = f2bf(acc[e]);
    }
}

// ---------------------------------------------------------------- CSR gather: g = sum ew*x[src]
__global__ __launch_bounds__(512) void agg_kernel(const ush_t* __restrict__ x,
                                                  const int* __restrict__ rp,
                                                  const uint2* __restrict__ csr,
                                                  ush_t* __restrict__ gH) {
    int t = threadIdx.x;
    int grp = t >> 5, c = t & 31;
    int n = blockIdx.x * 16 + grp;
    if (n >= NPAD) return;
    int nout = ((n >> 7) << 14) + ((c >> 3) << 12) + (((n >> 4) & 7) << 9)
             + (((c >> 1) & 3) << 7) + ((n & 15) << 3) + ((c & 1) << 2);
    if (n >= NN) {
        *(ushort4*)(gH + nout) = make_ushort4(0, 0, 0, 0);
        return;
    }
    int e0 = rp[n], e1 = rp[n + 1];
    float4 acc = make_float4(0.f, 0.f, 0.f, 0.f);
    int e = e0;
    for (; e + 1 < e1; e += 2) {
        uint2 r0 = csr[e], r1 = csr[e + 1];
        float w0 = __uint_as_float(r0.y), w1 = __uint_as_float(r1.y);
        ushort4 p0 = *(const ushort4*)(x + (size_t)r0.x * DD + c * 4);
        ushort4 p1 = *(const ushort4*)(x + (size_t)r1.x * DD + c * 4);
        acc.x += w0 * bf2f(p0.x) + w1 * bf2f(p1.x);
        acc.y += w0 * bf2f(p0.y) + w1 * bf2f(p1.y);
        acc.z += w0 * bf2f(p0.z) + w1 * bf2f(p1.z);
        acc.w += w0 * bf2f(p0.w) + w1 * bf2f(p1.w);
    }
    if (e < e1) {
        uint2 r0 = csr[e];
        float w0 = __uint_as_float(r0.y);
        ushort4 p0 = *(const ushort4*)(x + (size_t)r0.x * DD + c * 4);
        acc.x += w0 * bf2f(p0.x);
        acc.y += w0 * bf2f(p0.y);
        acc.z += w0 * bf2f(p0.z);
        acc.w += w0 * bf2f(p0.w);
    }
    ushort4 oh;
    oh.x = f2bf(acc.x); oh.y = f2bf(acc.y); oh.z = f2bf(acc.z); oh.w = f2bf(acc.w);
    *(ushort4*)(gH + nout) = oh;
}

// ---------------------------------------------------------------- GRU layer kernel (32-row tiles)
// 64 accumulator regs/thread + ~50 live → fits 4 waves/SIMD without spill.
// (R12 lesson: 128 acc regs at (256,4) spilled 200+ MB to scratch.)
__global__ __launch_bounds__(256, 4) void gru_kernel(const ush_t* __restrict__ xin,
                                                     const ush_t* __restrict__ gH,
                                                     ush_t* __restrict__ xout,
                                                     const ush_t* __restrict__ WB,
                                                     const float* __restrict__ bih,
                                                     const float* __restrict__ bhh,
                                                     int layer, int is_last,
                                                     const float* __restrict__ gw,
                                                     const float* __restrict__ gb,
                                                     float* __restrict__ accum,
                                                     float* __restrict__ den) {
    __shared__ ush_t sX[32 * 136];
    __shared__ float pl[32];
    __shared__ float sT[128];
    int t = threadIdx.x;
    int tb = blockIdx.x;
    int n0 = tb * 32;
    // --- stage x tile (row-major, padded pitch)
    #pragma unroll
    for (int it = 0; it < 2; ++it) {
        int idx = it * 256 + t;          // 512 chunks of 16B
        int row = idx >> 4, seg = idx & 15;
        ushort8_t v = *(const ushort8_t*)(xin + (size_t)(n0 + row) * DD + seg * 8);
        *(ushort8_t*)(sX + row * 136 + seg * 8) = v;
    }
    __syncthreads();
    // --- MFMA
    int l = t & 63, w = t >> 6;
    int lg = l >> 4, lc = l & 15;
    floatx4 accR[2][2], accZ[2][2], accN[2][2], accI[2][2];
    #pragma unroll
    for (int i = 0; i < 2; ++i)
        #pragma unroll
        for (int j = 0; j < 2; ++j) {
            accR[i][j] = (floatx4)0.f; accZ[i][j] = (floatx4)0.f;
            accN[i][j] = (floatx4)0.f; accI[i][j] = (floatx4)0.f;
        }
    int gbase = (tb >> 2) * 16384 + (tb & 3) * 1024 + lg * 128 + lc * 8;
    #pragma unroll
    for (int pass = 0; pass < 2; ++pass) {
        int matbase = pass ? (3 + layer * 3) : 0;
        #pragma unroll
        for (int kc = 0; kc < 4; ++kc) {
            short8 aHf[2];
            if (pass == 0) {
                #pragma unroll
                for (int i = 0; i < 2; ++i)
                    aHf[i] = *(const short8*)(sX + (i * 16 + lc) * 136 + kc * 32 + lg * 8);
            } else {
                #pragma unroll
                for (int i = 0; i < 2; ++i)
                    aHf[i] = *(const short8*)(gH + gbase + kc * 4096 + i * 512);
            }
            #pragma unroll
            for (int m3 = 0; m3 < 3; ++m3) {
                floatx4 (*accp)[2] = (m3 == 0) ? accR : (m3 == 1) ? accZ : (pass ? accI : accN);
                const ush_t* wb = WB + (size_t)((matbase + m3) * 4 + kc) * 4096;
                #pragma unroll
                for (int j = 0; j < 2; ++j) {
                    int boff = (((w * 2 + j) * 4 + lg) * 16 + lc) * 8;
                    short8 bH = *(const short8*)(wb + boff);
                    #pragma unroll
                    for (int i = 0; i < 2; ++i)
                        accp[i][j] = __builtin_amdgcn_mfma_f32_16x16x32_bf16(aHf[i], bH, accp[i][j], 0, 0, 0);
                }
            }
        }
    }
    __syncthreads();   // all sX A-frag reads done before overwrite
    // --- gates + blend, in-place into sX
    #pragma unroll
    for (int j = 0; j < 2; ++j) {
        int col = w * 32 + j * 16 + lc;
        float bIr = bih[col],       bHr = bhh[col];
        float bIz = bih[128 + col], bHz = bhh[128 + col];
        float bIn = bih[256 + col], bHn = bhh[256 + col];
        #pragma unroll
        for (int i = 0; i < 2; ++i)
            #pragma unroll
            for (int r = 0; r < 4; ++r) {
                int row = i * 16 + lg * 4 + r;
                float v = 0.f;
                if (n0 + row < NN) {
                    float rr = sigf(accR[i][j][r] + bIr + bHr);
                    float zz = sigf(accZ[i][j][r] + bIz + bHz);
                    float nn = tanhf_fast(accI[i][j][r] + bIn + rr * (accN[i][j][r] + bHn));
                    float h = bf2f(sX[row * 136 + col]);
                    v = (1.0f - zz) * nn + zz * h;
                }
                sX[row * 136 + col] = f2bf(v);
            }
    }
    __syncthreads();
    if (!is_last) {
        // --- coalesced row-major write-out
        #pragma unroll
        for (int it = 0; it < 2; ++it) {
            int idx = it * 256 + t;
            int row = idx >> 4, seg = idx & 15;
            ushort8_t v = *(const ushort8_t*)(sX + row * 136 + seg * 8);
            *(ushort8_t*)(xout + (size_t)(n0 + row) * DD + seg * 8) = v;
        }
    } else {
        // --- fused global-attention pooling (replicated accumulators)
        int row = t >> 3, q = t & 7;      // 8 threads per row, 16 cols each
        float s = 0.f;
        #pragma unroll
        for (int e = 0; e < 16; ++e)
            s += bf2f(sX[row * 136 + q * 16 + e]) * gw[q * 16 + e];
        s += __shfl_xor(s, 1);
        s += __shfl_xor(s, 2);
        s += __shfl_xor(s, 4);
        if (q == 0)
            pl[row] = (n0 + row < NN) ? __expf(sigf(s + gb[0])) : 0.f;
        __syncthreads();
        int cc = t & 127, half = t >> 7;
        float acc = 0.f;
        #pragma unroll
        for (int r = 0; r < 16; ++r)
            acc += pl[half * 16 + r] * bf2f(sX[(half * 16 + r) * 136 + cc]);
        if (half == 0) sT[cc] = acc;
        __syncthreads();
        if (half == 1) atomicAdd(&accum[(tb & 63) * 128 + cc], acc + sT[cc]);
        if (t < 32) {
            float v = pl[t];
            #pragma unroll
            for (int o = 16; o > 0; o >>= 1) v += __shfl_xor(v, o);
            if (t == 0) atomicAdd(&den[tb & 63], v);
        }
    }
}

__global__ void finalize_kernel(const float* __restrict__ accum, const float* __restrict__ den,
                                float* __restrict__ out) {
    __shared__ float dsum;
    int d = threadIdx.x;   // 128
    float s = 0.f;
    for (int rep = 0; rep < 64; ++rep) s += accum[rep * 128 + d];
    if (d == 0) {
        float ds = 0.f;
        for (int rep = 0; rep < 64; ++rep) ds += den[rep];
        dsum = ds;
    }
    __syncthreads();
    out[d] = s / dsum;
}

// ---------------------------------------------------------------- launch
extern "C" void kernel_launch(void* const* d_in, const int* in_sizes, int n_in,
                              void* d_out, int out_size, void* d_ws, size_t ws_size,
                              hipStream_t stream) {
    const int*   node_ids    = (const int*)d_in[0];
    const int*   edges       = (const int*)d_in[1];
    const int*   edge_types  = (const int*)d_in[2];
    const float* embed_table = (const float*)d_in[3];
    const float* edge_tab    = (const float*)d_in[4];
    const float* ggnn_w      = (const float*)d_in[5];
    const float* Wih         = (const float*)d_in[6];
    const float* Whh         = (const float*)d_in[7];
    const float* bih         = (const float*)d_in[8];
    const float* bhh         = (const float*)d_in[9];
    const float* gate_w      = (const float*)d_in[10];
    const float* gate_b      = (const float*)d_in[11];
    float* out = (float*)d_out;

    const size_t PL = (size_t)NPAD * DD;
    ush_t* wsb  = (ush_t*)d_ws;
    ush_t* xA   = wsb;
    ush_t* xB   = xA + PL;
    ush_t* gH   = xB + PL;          // frag plane
    ush_t* WB   = gH + PL;          // 15 mats * 4 chunks * 4096
    uint2* csr  = (uint2*)(WB + 15 * 4 * 4096);   // E records (8B-aligned)
    float* accum = (float*)(csr + NE);  // 64 * 128
    float* den   = accum + 64 * 128;    // 64
    float* rm    = den + 64;            // 7(+1)
    int*   rp    = (int*)(rm + 8);      // N+1
    int*   fill  = rp + NN + 1;         // N
    int*   bsum  = fill + NN;           // 128
    int*   boff  = bsum + 128;          // 128

    const int* src = edges;
    const int* dst = edges + NE;

    // one-time prep
    rowmean_kernel<<<7, 128, 0, stream>>>(edge_tab, rm);
    hipMemsetAsync(fill, 0, NN * sizeof(int), stream);
    hist_kernel<<<(NE + 255) / 256, 256, 0, stream>>>(dst, fill);
    scanA_kernel<<<SCANB, 1024, 0, stream>>>(fill, rp, bsum);
    scanB_kernel<<<1, 128, 0, stream>>>(bsum, boff);
    scanC_kernel<<<(NN + 255) / 256, 256, 0, stream>>>(rp, boff);
    hipMemsetAsync(fill, 0, NN * sizeof(int), stream);
    place_kernel<<<(NE + 255) / 256, 256, 0, stream>>>(src, dst, edge_types, rm, rp, fill, csr);
    embed_kernel<<<NPAD * 16 / 256, 256, 0, stream>>>(node_ids, embed_table, xA);
    wprep_kernel<<<192, 256, 0, stream>>>(Whh, WB);
    cprep_kernel<<<96, 256, 0, stream>>>(Wih, ggnn_w, WB);
    hipMemsetAsync(accum, 0, (64 * 128 + 64) * sizeof(float), stream);

    // 4 layers: standalone high-occupancy gather + gru
    ush_t* x = xA;
    ush_t* xo = xB;
    for (int layer = 0; layer < 4; ++layer) {
        agg_kernel<<<(NPAD + 15) / 16, 512, 0, stream>>>(x, rp, csr, gH);
        gru_kernel<<<NT3, 256, 0, stream>>>(x, gH, xo, WB, bih, bhh,
                                            layer, layer == 3 ? 1 : 0,
                                            gate_w, gate_b, accum, den);
        ush_t* tmp = x; x = xo; xo = tmp;
    }

    finalize_kernel<<<1, 128, 0, stream>>>(accum, den, out);
}